// Round 6
// baseline (199.942 us; speedup 1.0000x reference)
//
#include <hip/hip_runtime.h>

// GraphAttentionLayer: B=1, N=4096, F=256, H=8, U=64
//
// e_src cancels in softmax over j =>
//   out[i, u*8+h] = relu( (A @ (w*h))[i, h*64+u] / (A @ w)[i, h] ),  w = exp(e_dst)
// => ONE dense GEMM  C = A(4096x4096) x G(4096x544), G = [w*h (512) | w (8) | 0 (24)]
//
// R6: gemm was L2-BW-bound (80 KB B-loads per block-dstep; 655 MB device-wide).
//  - wave owns BOTH m-strips x unique n-tiles {w, w+8} (+tile16 on wave 0 only)
//    -> 34 KB/block-dstep, ~280 MB total B traffic.
//  - k_out fused into k_gemm epilogue via per-m-group completion counter
//    (last of 4 z-blocks re-reads P with atomicAdd(p,0) - coherent) -> 2 dispatches.
//
// Gtp layout (HW-verified R4/R5): tile (tk=k>>4, nt=n>>5), id=tk*17+nt, 1024 B:
//   u16[ id*512 + ((n&31) + 32*((k&15)>>3))*8 + (k&7) ]; B-frag(lane)=16B at id*1024+lane*16.
//
// ws: P @0 (8,912,896 B) | Gtp @8912896 (4,456,448 B) | cnt @13369344 (64 u32)

typedef unsigned short u16;
typedef unsigned int   u32;
typedef __attribute__((ext_vector_type(8)))  short  short8;    // 8 bf16 (4 VGPR)
typedef __attribute__((ext_vector_type(16))) float  floatx16;  // 32x32 MFMA acc
typedef __attribute__((ext_vector_type(8)))  unsigned short u16x8;
typedef __attribute__((ext_vector_type(4)))  unsigned short u16x4;

__device__ __forceinline__ u16 f2bf(float x) {
  u32 u = __float_as_uint(x);
  u += 0x7fffu + ((u >> 16) & 1u);   // RNE
  return (u16)(u >> 16);
}

__device__ __forceinline__ void async_ld16(const void* g, void* l) {
  __builtin_amdgcn_global_load_lds((const __attribute__((address_space(1))) void*)g,
                                   (__attribute__((address_space(3))) void*)l,
                                   16, 0, 0);
}

// ---------------------------------------------------------------------------
// Kernel 1: h = X@W (fp32, exact), e_dst -> w = exp, write Gtp (B-frag layout).
// Block: 32 j-rows x 128 c-cols (2 whole heads => e-sums block-local).
// Grid (128, 4) = 512 blocks = 2/CU. Also zeroes P and the completion counters.
// (R5 verbatim except cnt zeroing.)
// ---------------------------------------------------------------------------
__global__ __launch_bounds__(256) void k_hg(const float* __restrict__ X,
                                            const float* __restrict__ W,
                                            const float* __restrict__ av,
                                            u16* __restrict__ Gtp,
                                            float* __restrict__ P,
                                            u32* __restrict__ cnt) {
  __shared__ __align__(16) float Wc[64 * 128];   // 32 KB
  __shared__ __align__(16) float xs[64 * 36];    // 9 KB (pad 36 breaks stride)
  __shared__ float eL[64];
  __shared__ float w8L[64];
  const int t  = threadIdx.x;
  const int j0 = blockIdx.x * 32;
  const int y  = blockIdx.y;           // heads 2y, 2y+1
  const int c0 = y * 128;
  const int cq = t & 31, tj = t >> 5;

  // zero this block's P slab + counters
  {
    float4* P4 = (float4*)P;
    const int base = ((int)blockIdx.y * 128 + (int)blockIdx.x) * 1088;
    float4 z = {0.f, 0.f, 0.f, 0.f};
#pragma unroll
    for (int q = 0; q < 4; ++q) P4[base + q * 256 + t] = z;
    if (t < 64) P4[base + 1024 + t] = z;
    if (y == 0 && blockIdx.x < 64 && t == 0) cnt[blockIdx.x] = 0u;
  }
  if (t < 64) eL[t] = 0.f;

  float acc[4][4];
#pragma unroll
  for (int a = 0; a < 4; ++a)
#pragma unroll
    for (int b = 0; b < 4; ++b) acc[a][b] = 0.f;

  const int xjj = t >> 3, xoff = (t & 7) * 8;

  for (int cc = 0; cc < 4; ++cc) {
#pragma unroll
    for (int l = 0; l < 8; ++l) {
      int id = l * 256 + t;
      int kk = id >> 5, ch = id & 31;
      async_ld16(W + (size_t)(cc * 64 + kk) * 512 + c0 + ch * 4,
                 (char*)&Wc[0] + (size_t)(l * 256 + (t & 192)) * 16);
    }
    {
      const float* xp = X + (size_t)(j0 + xjj) * 256 + cc * 64 + xoff;
      float4 v0 = *(const float4*)xp;
      float4 v1 = *(const float4*)(xp + 4);
      xs[(xoff + 0) * 36 + xjj] = v0.x; xs[(xoff + 1) * 36 + xjj] = v0.y;
      xs[(xoff + 2) * 36 + xjj] = v0.z; xs[(xoff + 3) * 36 + xjj] = v0.w;
      xs[(xoff + 4) * 36 + xjj] = v1.x; xs[(xoff + 5) * 36 + xjj] = v1.y;
      xs[(xoff + 6) * 36 + xjj] = v1.z; xs[(xoff + 7) * 36 + xjj] = v1.w;
    }
    __syncthreads();
#pragma unroll 4
    for (int kk = 0; kk < 64; ++kk) {
      float4 w4 = *(const float4*)(&Wc[kk * 128 + cq * 4]);
      float4 xa = *(const float4*)(&xs[kk * 36 + tj * 4]);   // broadcast
      acc[0][0] += xa.x * w4.x; acc[0][1] += xa.x * w4.y; acc[0][2] += xa.x * w4.z; acc[0][3] += xa.x * w4.w;
      acc[1][0] += xa.y * w4.x; acc[1][1] += xa.y * w4.y; acc[1][2] += xa.y * w4.z; acc[1][3] += xa.y * w4.w;
      acc[2][0] += xa.z * w4.x; acc[2][1] += xa.z * w4.y; acc[2][2] += xa.z * w4.z; acc[2][3] += xa.z * w4.w;
      acc[3][0] += xa.w * w4.x; acc[3][1] += xa.w * w4.y; acc[3][2] += xa.w * w4.z; acc[3][3] += xa.w * w4.w;
    }
    __syncthreads();
  }

  // e_dst partials (2 block-local heads)
  const int lh = cq >> 4;
  {
    const float4 ad = *(const float4*)(av + 64 + (cq & 15) * 4);
#pragma unroll
    for (int jv = 0; jv < 4; ++jv) {
      float ep = acc[jv][0] * ad.x + acc[jv][1] * ad.y + acc[jv][2] * ad.z + acc[jv][3] * ad.w;
      atomicAdd(&eL[(tj * 4 + jv) * 2 + lh], ep);
    }
  }
  __syncthreads();
  if (t < 64) {
    float e = fminf(30.f, fmaxf(-30.f, eL[t]));
    w8L[t] = __expf(e);
  }
  __syncthreads();

  // scaled bf16 stores in B-frag layout
  const int tk  = (j0 >> 4) + (tj >> 2);
  const int khh = (tj >> 1) & 1;
  const int jlo = (tj & 1) * 4;
#pragma unroll
  for (int cv = 0; cv < 4; ++cv) {
    int n  = c0 + cq * 4 + cv;
    int nt = n >> 5;
    u16x4 o;
#pragma unroll
    for (int jv = 0; jv < 4; ++jv)
      o[jv] = f2bf(acc[jv][cv] * w8L[(tj * 4 + jv) * 2 + lh]);
    *(u16x4*)(Gtp + (size_t)(tk * 17 + nt) * 512 + ((n & 31) + 32 * khh) * 8 + jlo) = o;
  }
  // den rows (n = 512 + h, this block's 2 heads x 32 rows)
  if (t < 64) {
    int jj = t >> 1, lh2 = t & 1, h = 2 * y + lh2, j = j0 + jj;
    Gtp[(size_t)((j >> 4) * 17 + 16) * 512 + (h + 32 * ((jj & 15) >> 3)) * 8 + (jj & 7)] =
        f2bf(w8L[jj * 2 + lh2]);
  }
  // zero pad (n in [520,544)): slots [8,32) and [40,64) of tile nt=16
  if (y == 3 && t < 96) {
    int tk2 = t / 48, r = t - tk2 * 48;
    int slot = (r < 24) ? (8 + r) : (16 + r);
    u16x8 z = {0, 0, 0, 0, 0, 0, 0, 0};
    *(u16x8*)(Gtp + (size_t)(((j0 >> 4) + tk2) * 17 + 16) * 512 + slot * 8) = z;
  }
}

// ---------------------------------------------------------------------------
// Kernel 2: C += A x G^T (32x32x16 bf16 MFMA) -> atomicAdd P; last z-block per
// m-group computes out. Block: 512 thr = 8 waves, M=64. Wave w: n-tiles
// {w, w+8} x both m-strips (B loaded once, zero duplication); wave 0 also
// tile 16 (den). A: K=256 chunks fp32->bf16 XOR-swizzled dbuf LDS (R5-verbatim
// staging). B: direct dwordx4 from L2-hot Gtp, barrier-free inner 8 dsteps.
// Grid (64, 4) = 256 blocks = 1/CU (all co-resident).
// ---------------------------------------------------------------------------
__global__ __launch_bounds__(512) void k_gemm(const float* __restrict__ A,
                                              const u16* __restrict__ Gtp,
                                              float* P,
                                              float* __restrict__ out,
                                              u32* cnt) {
  __shared__ __align__(16) u16 As[2][64 * 256];  // 2 x 32 KB
  __shared__ u32 sdone;
  const int t    = threadIdx.x;
  const int i0   = blockIdx.x * 64;
  const int kt0  = blockIdx.y * 1024;
  const int w    = t >> 6, lane = t & 63;
  const int ml   = lane & 31, kh = lane >> 5;
  const int nt0  = w, nt1 = w + 8;

  floatx16 acc[2][2];                  // [tile][strip]
  floatx16 accd[2];                    // wave0 den tile [strip]
#pragma unroll
  for (int a = 0; a < 2; ++a)
#pragma unroll
    for (int s = 0; s < 2; ++s)
#pragma unroll
      for (int r = 0; r < 16; ++r) { acc[a][s][r] = 0.f; if (a == 0) accd[s][r] = 0.f; }

  // A staging (R5-verified): thread -> row ar, q-th float4 at k=(t&7)*4+q*32
  const int ar  = t >> 3;
  const int af  = (t & 7) * 4;
  const float* pa = A + (size_t)(i0 + ar) * 4096 + kt0 + af;
  const int sbase = ar * 256 + (t & 1) * 4;
  const int scb   = (t & 7) >> 1;
  const int arx   = ar & 7;
  // A-frag reads: strips at rows ml and 32+ml; chunk c -> physical c^(ml&7)
  const int mx    = ml & 7;
  const int r0off = ml * 256;
  const int r1off = (32 + ml) * 256;

  float4 areg[8];
#pragma unroll
  for (int q = 0; q < 8; ++q) areg[q] = *(const float4*)(pa + q * 32);
#pragma unroll
  for (int q = 0; q < 8; ++q) {
    u16x4 v = {f2bf(areg[q].x), f2bf(areg[q].y), f2bf(areg[q].z), f2bf(areg[q].w)};
    *(u16x4*)(&As[0][sbase + ((q * 4 + scb) ^ arx) * 8]) = v;
  }
  __syncthreads();

  for (int cc = 0; cc < 4; ++cc) {
    const int cb = cc & 1;
    if (cc < 3) {
#pragma unroll
      for (int q = 0; q < 8; ++q)
        areg[q] = *(const float4*)(pa + (cc + 1) * 256 + q * 32);
    }
    const int ktb = (kt0 >> 4) + cc * 16;
#pragma unroll
    for (int ds = 0; ds < 8; ++ds) {
      const size_t kta = (size_t)(ktb + ds * 2);
      short8 b00 = *(const short8*)(Gtp + (kta * 17 + nt0) * 512 + lane * 8);
      short8 b01 = *(const short8*)(Gtp + ((kta + 1) * 17 + nt0) * 512 + lane * 8);
      short8 b10 = *(const short8*)(Gtp + (kta * 17 + nt1) * 512 + lane * 8);
      short8 b11 = *(const short8*)(Gtp + ((kta + 1) * 17 + nt1) * 512 + lane * 8);
      short8 a00 = *(const short8*)(&As[cb][r0off + ((ds * 4 + kh) ^ mx) * 8]);
      short8 a01 = *(const short8*)(&As[cb][r0off + ((ds * 4 + 2 + kh) ^ mx) * 8]);
      short8 a10 = *(const short8*)(&As[cb][r1off + ((ds * 4 + kh) ^ mx) * 8]);
      short8 a11 = *(const short8*)(&As[cb][r1off + ((ds * 4 + 2 + kh) ^ mx) * 8]);
      acc[0][0] = __builtin_amdgcn_mfma_f32_32x32x16_bf16(a00, b00, acc[0][0], 0, 0, 0);
      acc[0][1] = __builtin_amdgcn_mfma_f32_32x32x16_bf16(a10, b00, acc[0][1], 0, 0, 0);
      acc[1][0] = __builtin_amdgcn_mfma_f32_32x32x16_bf16(a00, b10, acc[1][0], 0, 0, 0);
      acc[1][1] = __builtin_amdgcn_mfma_f32_32x32x16_bf16(a10, b10, acc[1][1], 0, 0, 0);
      acc[0][0] = __builtin_amdgcn_mfma_f32_32x32x16_bf16(a01, b01, acc[0][0], 0, 0, 0);
      acc[0][1] = __builtin_amdgcn_mfma_f32_32x32x16_bf16(a11, b01, acc[0][1], 0, 0, 0);
      acc[1][0] = __builtin_amdgcn_mfma_f32_32x32x16_bf16(a01, b11, acc[1][0], 0, 0, 0);
      acc[1][1] = __builtin_amdgcn_mfma_f32_32x32x16_bf16(a11, b11, acc[1][1], 0, 0, 0);
      if (w == 0) {                    // den tile (wave-uniform branch)
        short8 b20 = *(const short8*)(Gtp + (kta * 17 + 16) * 512 + lane * 8);
        short8 b21 = *(const short8*)(Gtp + ((kta + 1) * 17 + 16) * 512 + lane * 8);
        accd[0] = __builtin_amdgcn_mfma_f32_32x32x16_bf16(a00, b20, accd[0], 0, 0, 0);
        accd[1] = __builtin_amdgcn_mfma_f32_32x32x16_bf16(a10, b20, accd[1], 0, 0, 0);
        accd[0] = __builtin_amdgcn_mfma_f32_32x32x16_bf16(a01, b21, accd[0], 0, 0, 0);
        accd[1] = __builtin_amdgcn_mfma_f32_32x32x16_bf16(a11, b21, accd[1], 0, 0, 0);
      }
    }
    if (cc < 3) {
      __syncthreads();
#pragma unroll
      for (int q = 0; q < 8; ++q) {
        u16x4 v = {f2bf(areg[q].x), f2bf(areg[q].y), f2bf(areg[q].z), f2bf(areg[q].w)};
        *(u16x4*)(&As[cb ^ 1][sbase + ((q * 4 + scb) ^ arx) * 8]) = v;
      }
      __syncthreads();
    }
  }

  // epilogue: C/D col=lane&31, row=(r&3)+8*(r>>2)+4*(lane>>5); atomic accumulate
#pragma unroll
  for (int tl = 0; tl < 2; ++tl) {
    int n = (w + tl * 8) * 32 + ml;           // always < 512
#pragma unroll
    for (int s = 0; s < 2; ++s)
#pragma unroll
      for (int r = 0; r < 16; ++r) {
        int row = i0 + s * 32 + 4 * kh + (r & 3) + 8 * (r >> 2);
        atomicAdd(P + (size_t)row * 544 + n, acc[tl][s][r]);
      }
  }
  if (w == 0 && ml < 8) {
    int n = 512 + ml;
#pragma unroll
    for (int s = 0; s < 2; ++s)
#pragma unroll
      for (int r = 0; r < 16; ++r) {
        int row = i0 + s * 32 + 4 * kh + (r & 3) + 8 * (r >> 2);
        atomicAdd(P + (size_t)row * 544 + n, accd[s][r]);
      }
  }

  // last-of-4 z-blocks for this m-group computes out for rows i0..i0+63
  __syncthreads();                      // drains all waves' atomics (vmcnt)
  if (t == 0) { __threadfence(); sdone = atomicAdd(&cnt[blockIdx.x], 1u); }
  __syncthreads();
  if (sdone == 3u) {
    float* fb = (float*)&As[0][0];      // per-wave 544-float row buffer
    for (int rr = 0; rr < 8; ++rr) {
      int row = i0 + w * 8 + rr;
      float* pr = P + (size_t)row * 544;
      for (int c = lane; c < 544; c += 64)
        fb[w * 544 + c] = atomicAdd(pr + c, 0.f);   // coherent read-back
      for (int c = lane; c < 512; c += 64) {        // c = u*8 + h
        int u = c >> 3, hd = c & 7;
        float o = fb[w * 544 + hd * 64 + u] / fb[w * 544 + 512 + hd];
        out[(size_t)row * 512 + c] = fmaxf(o, 0.f);
      }
    }
  }
}

extern "C" void kernel_launch(void* const* d_in, const int* in_sizes, int n_in,
                              void* d_out, int out_size, void* d_ws, size_t ws_size,
                              hipStream_t stream) {
  const float* X  = (const float*)d_in[0];
  const float* A  = (const float*)d_in[1];
  const float* W  = (const float*)d_in[2];
  const float* av = (const float*)d_in[3];
  float* out = (float*)d_out;
  char*  ws  = (char*)d_ws;

  float* P   = (float*)ws;                 // 4096*544*4
  u16*   Gtp = (u16*)(ws + 8912896);       // 256*17 tiles * 1024 B
  u32*   cnt = (u32*)(ws + 13369344);      // 64 completion counters

  k_hg<<<dim3(128, 4), 256, 0, stream>>>(X, W, av, Gtp, P, cnt);
  k_gemm<<<dim3(64, 4), 512, 0, stream>>>(A, Gtp, P, out, cnt);
}